// Round 1
// baseline (372.979 us; speedup 1.0000x reference)
//
#include <hip/hip_runtime.h>
#include <hip/hip_bf16.h>

#define SEQ 2048
#define DM 1024
#define NB 4

typedef short bf16x8 __attribute__((ext_vector_type(8)));
typedef float f32x4 __attribute__((ext_vector_type(4)));
typedef float f32x4v __attribute__((ext_vector_type(4)));
typedef unsigned short u16x4 __attribute__((ext_vector_type(4)));
typedef unsigned short u16x8 __attribute__((ext_vector_type(8)));

__device__ __forceinline__ float bf2f(unsigned short u) {
  union { unsigned int i; float f; } w; w.i = ((unsigned int)u) << 16; return w.f;
}
__device__ __forceinline__ unsigned short f2bf(float f) {
  union { __hip_bfloat16 h; unsigned short u; } w; w.h = __float2bfloat16(f); return w.u;
}
__device__ __forceinline__ void load_lds16(const void* g, void* l) {
  __builtin_amdgcn_global_load_lds((const __attribute__((address_space(1))) void*)g,
                                   (__attribute__((address_space(3))) void*)l, 16, 0, 0);
}

// f32 -> bf16 conversion (vectorized, grid-stride)
__global__ __launch_bounds__(256) void cvt_kernel(const float* __restrict__ in,
                                                  unsigned short* __restrict__ out, int n4) {
  int idx = blockIdx.x * 256 + threadIdx.x;
  int stride = gridDim.x * 256;
  for (int i = idx; i < n4; i += stride) {
    f32x4v x = ((const f32x4v*)in)[i];
    u16x4 o;
    o[0] = f2bf(x[0]); o[1] = f2bf(x[1]); o[2] = f2bf(x[2]); o[3] = f2bf(x[3]);
    ((u16x4*)out)[i] = o;
  }
}

// C = A * B^T (+bias) (*scale). A: MxK row-major (lda), B: NxK row-major (ldb).
// 128x128 tile, BK=64, 4 waves (2x2), 16x16x32 bf16 MFMA.
// LDS XOR-swizzled (slot ^= row&7) so ds_read_b128 is ~conflict-free;
// global source address is pre-swizzled since global_load_lds writes linearly.
__global__ __launch_bounds__(256, 2) void gemm_bt(
    const unsigned short* __restrict__ A, int lda, long sA,
    const unsigned short* __restrict__ B, int ldb, long sB,
    void* __restrict__ Cv, int ldc, long sC,
    int K, const float* __restrict__ bias, float scale, int outf32)
{
  __shared__ unsigned short As[128 * 64];
  __shared__ unsigned short Bs[128 * 64];
  const int tid = threadIdx.x;
  const int lane = tid & 63;
  const int wave = tid >> 6;
  const int wm = wave >> 1, wn = wave & 1;
  const int m0 = blockIdx.x * 128, n0 = blockIdx.y * 128;
  const unsigned short* Ab = A + (size_t)sA * blockIdx.z;
  const unsigned short* Bb = B + (size_t)sB * blockIdx.z;

  f32x4 acc[4][4];
#pragma unroll
  for (int i = 0; i < 4; ++i)
#pragma unroll
    for (int j = 0; j < 4; ++j)
      acc[i][j] = (f32x4){0.f, 0.f, 0.f, 0.f};

  const int nk = K >> 6;
  for (int kt = 0; kt < nk; ++kt) {
    __syncthreads();  // previous iter's reads done before overwriting LDS
    const int kb = kt << 6;
#pragma unroll
    for (int it = 0; it < 4; ++it) {
      int c = it * 256 + tid;
      int row = c >> 3;
      int lslot = (c & 7) ^ (row & 7);   // pre-swizzled global source column
      int ldsoff = (it * 256 + wave * 64) * 8;  // wave-uniform linear LDS dest
      load_lds16(Ab + (size_t)(m0 + row) * lda + kb + lslot * 8, &As[ldsoff]);
      load_lds16(Bb + (size_t)(n0 + row) * ldb + kb + lslot * 8, &Bs[ldsoff]);
    }
    __syncthreads();  // drains vmcnt(0): staged tile visible
#pragma unroll
    for (int h = 0; h < 2; ++h) {
      bf16x8 af[4], bfr[4];
#pragma unroll
      for (int i = 0; i < 4; ++i) {
        int row = wm * 64 + i * 16 + (lane & 15);
        int pslot = (h * 4 + (lane >> 4)) ^ (row & 7);
        af[i] = *(const bf16x8*)&As[row * 64 + pslot * 8];
      }
#pragma unroll
      for (int j = 0; j < 4; ++j) {
        int row = wn * 64 + j * 16 + (lane & 15);
        int pslot = (h * 4 + (lane >> 4)) ^ (row & 7);
        bfr[j] = *(const bf16x8*)&Bs[row * 64 + pslot * 8];
      }
#pragma unroll
      for (int i = 0; i < 4; ++i)
#pragma unroll
        for (int j = 0; j < 4; ++j)
          acc[i][j] = __builtin_amdgcn_mfma_f32_16x16x32_bf16(af[i], bfr[j], acc[i][j], 0, 0, 0);
    }
  }

  // C/D layout: col = lane&15, row = (lane>>4)*4 + reg  (m89-verified)
  const int rsub = (lane >> 4) * 4;
  const int cbase = n0 + wn * 64 + (lane & 15);
  if (outf32) {
    float* C = (float*)Cv + (size_t)sC * blockIdx.z;
#pragma unroll
    for (int i = 0; i < 4; ++i) {
      int rbase = m0 + wm * 64 + i * 16 + rsub;
#pragma unroll
      for (int j = 0; j < 4; ++j)
#pragma unroll
        for (int r = 0; r < 4; ++r)
          C[(size_t)(rbase + r) * ldc + cbase + j * 16] = acc[i][j][r] * scale;
    }
  } else {
    unsigned short* C = (unsigned short*)Cv + (size_t)sC * blockIdx.z;
    float bv[4] = {0.f, 0.f, 0.f, 0.f};
    if (bias) {
#pragma unroll
      for (int j = 0; j < 4; ++j) bv[j] = bias[cbase + j * 16];
    }
#pragma unroll
    for (int i = 0; i < 4; ++i) {
      int rbase = m0 + wm * 64 + i * 16 + rsub;
#pragma unroll
      for (int j = 0; j < 4; ++j)
#pragma unroll
        for (int r = 0; r < 4; ++r)
          C[(size_t)(rbase + r) * ldc + cbase + j * 16] = f2bf(acc[i][j][r] + bv[j]);
    }
  }
}

// vt[b][d][s] = v[b][s][d]  (64x64 LDS tile transpose)
__global__ __launch_bounds__(256) void transpose_kernel(const unsigned short* __restrict__ v,
                                                        unsigned short* __restrict__ vt) {
  __shared__ unsigned short t[64][65];
  int b = blockIdx.z;
  int s0 = blockIdx.x * 64;
  int d0 = blockIdx.y * 64;
  int tid = threadIdx.x;
  int rr = tid >> 3;          // 0..31
  int c8 = (tid & 7) * 8;     // 0..56
#pragma unroll
  for (int it = 0; it < 2; ++it) {
    int row = rr + it * 32;
    u16x8 val = *(const u16x8*)&v[((size_t)b * SEQ + s0 + row) * DM + d0 + c8];
#pragma unroll
    for (int j = 0; j < 8; ++j) t[row][c8 + j] = val[j];
  }
  __syncthreads();
#pragma unroll
  for (int it = 0; it < 2; ++it) {
    int drow = rr + it * 32;
    u16x8 o;
#pragma unroll
    for (int j = 0; j < 8; ++j) o[j] = t[c8 + j][drow];
    *(u16x8*)&vt[((size_t)b * DM + d0 + drow) * SEQ + s0 + c8] = o;
  }
}

// row softmax over SEQ f32 -> bf16 probs. one block per row.
__global__ __launch_bounds__(256) void softmax_kernel(const float* __restrict__ Sc,
                                                      unsigned short* __restrict__ P) {
  int row = blockIdx.x;
  int tid = threadIdx.x;
  const float* sr = Sc + (size_t)row * SEQ;
  float v[8];
  f32x4v a = ((const f32x4v*)sr)[tid * 2];
  f32x4v b = ((const f32x4v*)sr)[tid * 2 + 1];
  v[0]=a[0]; v[1]=a[1]; v[2]=a[2]; v[3]=a[3];
  v[4]=b[0]; v[5]=b[1]; v[6]=b[2]; v[7]=b[3];
  float m = v[0];
#pragma unroll
  for (int j = 1; j < 8; ++j) m = fmaxf(m, v[j]);
#pragma unroll
  for (int off = 32; off; off >>= 1) m = fmaxf(m, __shfl_xor(m, off));
  __shared__ float red[8];
  int wv = tid >> 6;
  if ((tid & 63) == 0) red[wv] = m;
  __syncthreads();
  m = fmaxf(fmaxf(red[0], red[1]), fmaxf(red[2], red[3]));
  float s = 0.f;
#pragma unroll
  for (int j = 0; j < 8; ++j) { v[j] = __expf(v[j] - m); s += v[j]; }
#pragma unroll
  for (int off = 32; off; off >>= 1) s += __shfl_xor(s, off);
  if ((tid & 63) == 0) red[4 + wv] = s;
  __syncthreads();
  s = red[4] + red[5] + red[6] + red[7];
  float inv = 1.f / s;
  u16x8 o;
#pragma unroll
  for (int j = 0; j < 8; ++j) o[j] = f2bf(v[j] * inv);
  *(u16x8*)&P[(size_t)row * SEQ + tid * 8] = o;
}

// y = LN(x + res(masked)) * g + b. x from f32 (xf) or bf16 (xb); out f32 or bf16.
__global__ __launch_bounds__(256) void ln_kernel(
    const float* __restrict__ xf, const unsigned short* __restrict__ xb,
    const unsigned short* __restrict__ res, int masked,
    const float* __restrict__ g, const float* __restrict__ be,
    float* __restrict__ outf, unsigned short* __restrict__ outb)
{
  int row = blockIdx.x;
  int s = row & (SEQ - 1);
  int tid = threadIdx.x;
  int d0 = tid * 4;
  float v[4];
  if (xf) {
    f32x4v t = ((const f32x4v*)(xf + (size_t)row * DM))[tid];
    v[0]=t[0]; v[1]=t[1]; v[2]=t[2]; v[3]=t[3];
  } else {
    u16x4 t = ((const u16x4*)(xb + (size_t)row * DM))[tid];
    v[0]=bf2f(t[0]); v[1]=bf2f(t[1]); v[2]=bf2f(t[2]); v[3]=bf2f(t[3]);
  }
  u16x4 rv = ((const u16x4*)(res + (size_t)row * DM))[tid];
#pragma unroll
  for (int j = 0; j < 4; ++j) {
    float r = bf2f(rv[j]);
    if (masked && (d0 + j) > s) r = 0.f;  // tril on attention OUTPUT: keep d<=s
    v[j] += r;
  }
  float s1 = v[0] + v[1] + v[2] + v[3];
  float s2 = v[0]*v[0] + v[1]*v[1] + v[2]*v[2] + v[3]*v[3];
#pragma unroll
  for (int off = 32; off; off >>= 1) { s1 += __shfl_xor(s1, off); s2 += __shfl_xor(s2, off); }
  __shared__ float red[8];
  int wv = tid >> 6;
  if ((tid & 63) == 0) { red[wv] = s1; red[4 + wv] = s2; }
  __syncthreads();
  s1 = red[0] + red[1] + red[2] + red[3];
  s2 = red[4] + red[5] + red[6] + red[7];
  float mean = s1 * (1.f / DM);
  float var = s2 * (1.f / DM) - mean * mean;
  float rstd = rsqrtf(var + 1e-5f);
  f32x4v gv = ((const f32x4v*)g)[tid];
  f32x4v bv = ((const f32x4v*)be)[tid];
  if (outf) {
    f32x4v o;
#pragma unroll
    for (int j = 0; j < 4; ++j) o[j] = (v[j] - mean) * rstd * gv[j] + bv[j];
    ((f32x4v*)(outf + (size_t)row * DM))[tid] = o;
  } else {
    u16x4 o;
#pragma unroll
    for (int j = 0; j < 4; ++j) o[j] = f2bf((v[j] - mean) * rstd * gv[j] + bv[j]);
    ((u16x4*)(outb + (size_t)row * DM))[tid] = o;
  }
}

extern "C" void kernel_launch(void* const* d_in, const int* in_sizes, int n_in,
                              void* d_out, int out_size, void* d_ws, size_t ws_size,
                              hipStream_t stream) {
  (void)in_sizes; (void)n_in; (void)out_size; (void)ws_size;
  const float* x     = (const float*)d_in[0];
  const float* wq_w  = (const float*)d_in[1];
  const float* wq_b  = (const float*)d_in[2];
  const float* wk_w  = (const float*)d_in[3];
  const float* wk_b  = (const float*)d_in[4];
  const float* wv_w  = (const float*)d_in[5];
  const float* wv_b  = (const float*)d_in[6];
  const float* lin_w = (const float*)d_in[7];
  const float* lin_b = (const float*)d_in[8];
  const float* g1    = (const float*)d_in[9];
  const float* b1    = (const float*)d_in[10];
  const float* g2    = (const float*)d_in[11];
  const float* b2    = (const float*)d_in[12];

  const size_t SD = (size_t)NB * SEQ * DM;  // 8,388,608 elems
  // ws layout (ushort elems unless noted): total ~168 MB
  unsigned short* xb   = (unsigned short*)d_ws;
  unsigned short* q    = xb + SD;
  unsigned short* k    = q + SD;
  unsigned short* v    = k + SD;
  unsigned short* vt   = v + SD;
  unsigned short* attn = vt + SD;
  unsigned short* x1   = attn + SD;
  unsigned short* lin  = x1 + SD;
  float* sc            = (float*)(lin + SD);           // SEQ*SEQ f32 (per-batch reuse)
  unsigned short* P    = (unsigned short*)(sc + (size_t)SEQ * SEQ);
  unsigned short* wqb  = P + (size_t)SEQ * SEQ;
  unsigned short* wkb  = wqb + DM * DM;
  unsigned short* wvb  = wkb + DM * DM;
  unsigned short* lwb  = wvb + DM * DM;

  cvt_kernel<<<2048, 256, 0, stream>>>(x, xb, (int)(SD / 4));
  cvt_kernel<<<1024, 256, 0, stream>>>(wq_w, wqb, DM * DM / 4);
  cvt_kernel<<<1024, 256, 0, stream>>>(wk_w, wkb, DM * DM / 4);
  cvt_kernel<<<1024, 256, 0, stream>>>(wv_w, wvb, DM * DM / 4);
  cvt_kernel<<<1024, 256, 0, stream>>>(lin_w, lwb, DM * DM / 4);

  // Q/K/V projections: [8192,1024] = x * W^T + b
  gemm_bt<<<dim3(64, 8, 1), 256, 0, stream>>>(xb, DM, 0, wqb, DM, 0, q, DM, 0, DM, wq_b, 1.f, 0);
  gemm_bt<<<dim3(64, 8, 1), 256, 0, stream>>>(xb, DM, 0, wkb, DM, 0, k, DM, 0, DM, wk_b, 1.f, 0);
  gemm_bt<<<dim3(64, 8, 1), 256, 0, stream>>>(xb, DM, 0, wvb, DM, 0, v, DM, 0, DM, wv_b, 1.f, 0);
  transpose_kernel<<<dim3(SEQ / 64, DM / 64, NB), 256, 0, stream>>>(v, vt);

  const float scale = 0.03125f;  // 1/sqrt(1024)
  for (int b = 0; b < NB; ++b) {
    const unsigned short* qb2 = q + (size_t)b * SEQ * DM;
    const unsigned short* kb2 = k + (size_t)b * SEQ * DM;
    const unsigned short* vtb = vt + (size_t)b * DM * SEQ;
    unsigned short* ab = attn + (size_t)b * SEQ * DM;
    gemm_bt<<<dim3(16, 16, 1), 256, 0, stream>>>(qb2, DM, 0, kb2, DM, 0, sc, SEQ, 0, DM, nullptr, scale, 1);
    softmax_kernel<<<SEQ, 256, 0, stream>>>(sc, P);
    gemm_bt<<<dim3(16, 8, 1), 256, 0, stream>>>(P, SEQ, 0, vtb, SEQ, 0, ab, DM, 0, SEQ, nullptr, 1.f, 0);
  }

  // LN1(x + tril(attn)) -> x1 (bf16)
  ln_kernel<<<NB * SEQ, 256, 0, stream>>>(x, nullptr, attn, 1, g1, b1, nullptr, x1);
  // linear = x1 * lin_w^T + lin_b
  gemm_bt<<<dim3(64, 8, 1), 256, 0, stream>>>(x1, DM, 0, lwb, DM, 0, lin, DM, 0, DM, lin_b, 1.f, 0);
  // LN2(x1 + linear) -> d_out (f32)
  ln_kernel<<<NB * SEQ, 256, 0, stream>>>(nullptr, x1, lin, 0, g2, b2, (float*)d_out, nullptr);
}

// Round 3
// 235.722 us; speedup vs baseline: 1.5823x; 1.5823x over previous
//
#include <hip/hip_runtime.h>
#include <hip/hip_bf16.h>

#define SEQ 2048
#define DM 1024
#define NB 4

typedef short bf16x8 __attribute__((ext_vector_type(8)));
typedef float f32x4 __attribute__((ext_vector_type(4)));
typedef float f32x4v __attribute__((ext_vector_type(4)));
typedef unsigned short u16x4 __attribute__((ext_vector_type(4)));
typedef unsigned short u16x8 __attribute__((ext_vector_type(8)));

__device__ __forceinline__ float bf2f(unsigned short u) {
  union { unsigned int i; float f; } w; w.i = ((unsigned int)u) << 16; return w.f;
}
__device__ __forceinline__ unsigned short f2bf(float f) {
  union { __hip_bfloat16 h; unsigned short u; } w; w.h = __float2bfloat16(f); return w.u;
}
__device__ __forceinline__ void load_lds16(const void* g, void* l) {
  __builtin_amdgcn_global_load_lds((const __attribute__((address_space(1))) void*)g,
                                   (__attribute__((address_space(3))) void*)l, 16, 0, 0);
}

// f32 -> bf16 conversion (vectorized, grid-stride)
__global__ __launch_bounds__(256) void cvt_kernel(const float* __restrict__ in,
                                                  unsigned short* __restrict__ out, int n4) {
  int idx = blockIdx.x * 256 + threadIdx.x;
  int stride = gridDim.x * 256;
  for (int i = idx; i < n4; i += stride) {
    f32x4v x = ((const f32x4v*)in)[i];
    u16x4 o;
    o[0] = f2bf(x[0]); o[1] = f2bf(x[1]); o[2] = f2bf(x[2]); o[3] = f2bf(x[3]);
    ((u16x4*)out)[i] = o;
  }
}

// C = A * B^T (+bias) (*scale). A: MxK row-major (lda), B: NxK row-major (ldb).
// 128x128 tile, BK=64, 4 waves (2x2), 16x16x32 bf16 MFMA.
// LDS XOR-swizzled (slot ^= row&7) so ds_read_b128 is ~conflict-free;
// global source address is pre-swizzled since global_load_lds writes linearly.
__global__ __launch_bounds__(256, 2) void gemm_bt(
    const unsigned short* __restrict__ A, int lda, long sA,
    const unsigned short* __restrict__ B, int ldb, long sB,
    void* __restrict__ Cv, int ldc, long sC,
    int K, const float* __restrict__ bias, float scale, int outf32)
{
  __shared__ unsigned short As[128 * 64];
  __shared__ unsigned short Bs[128 * 64];
  const int tid = threadIdx.x;
  const int lane = tid & 63;
  const int wave = tid >> 6;
  const int wm = wave >> 1, wn = wave & 1;
  const int m0 = blockIdx.x * 128, n0 = blockIdx.y * 128;
  const unsigned short* Ab = A + (size_t)sA * blockIdx.z;
  const unsigned short* Bb = B + (size_t)sB * blockIdx.z;

  f32x4 acc[4][4];
#pragma unroll
  for (int i = 0; i < 4; ++i)
#pragma unroll
    for (int j = 0; j < 4; ++j)
      acc[i][j] = (f32x4){0.f, 0.f, 0.f, 0.f};

  const int nk = K >> 6;
  for (int kt = 0; kt < nk; ++kt) {
    __syncthreads();  // previous iter's reads done before overwriting LDS
    const int kb = kt << 6;
#pragma unroll
    for (int it = 0; it < 4; ++it) {
      int c = it * 256 + tid;
      int row = c >> 3;
      int lslot = (c & 7) ^ (row & 7);   // pre-swizzled global source column
      int ldsoff = (it * 256 + wave * 64) * 8;  // wave-uniform linear LDS dest
      load_lds16(Ab + (size_t)(m0 + row) * lda + kb + lslot * 8, &As[ldsoff]);
      load_lds16(Bb + (size_t)(n0 + row) * ldb + kb + lslot * 8, &Bs[ldsoff]);
    }
    __syncthreads();  // drains vmcnt(0): staged tile visible
#pragma unroll
    for (int h = 0; h < 2; ++h) {
      bf16x8 af[4], bfr[4];
#pragma unroll
      for (int i = 0; i < 4; ++i) {
        int row = wm * 64 + i * 16 + (lane & 15);
        int pslot = (h * 4 + (lane >> 4)) ^ (row & 7);
        af[i] = *(const bf16x8*)&As[row * 64 + pslot * 8];
      }
#pragma unroll
      for (int j = 0; j < 4; ++j) {
        int row = wn * 64 + j * 16 + (lane & 15);
        int pslot = (h * 4 + (lane >> 4)) ^ (row & 7);
        bfr[j] = *(const bf16x8*)&Bs[row * 64 + pslot * 8];
      }
#pragma unroll
      for (int i = 0; i < 4; ++i)
#pragma unroll
        for (int j = 0; j < 4; ++j)
          acc[i][j] = __builtin_amdgcn_mfma_f32_16x16x32_bf16(af[i], bfr[j], acc[i][j], 0, 0, 0);
    }
  }

  // C/D layout: col = lane&15, row = (lane>>4)*4 + reg  (m89-verified)
  const int rsub = (lane >> 4) * 4;
  const int cbase = n0 + wn * 64 + (lane & 15);
  if (outf32) {
    float* C = (float*)Cv + (size_t)sC * blockIdx.z;
#pragma unroll
    for (int i = 0; i < 4; ++i) {
      int rbase = m0 + wm * 64 + i * 16 + rsub;
#pragma unroll
      for (int j = 0; j < 4; ++j)
#pragma unroll
        for (int r = 0; r < 4; ++r)
          C[(size_t)(rbase + r) * ldc + cbase + j * 16] = acc[i][j][r] * scale;
    }
  } else {
    unsigned short* C = (unsigned short*)Cv + (size_t)sC * blockIdx.z;
    float bv[4] = {0.f, 0.f, 0.f, 0.f};
    if (bias) {
#pragma unroll
      for (int j = 0; j < 4; ++j) bv[j] = bias[cbase + j * 16];
    }
#pragma unroll
    for (int i = 0; i < 4; ++i) {
      int rbase = m0 + wm * 64 + i * 16 + rsub;
#pragma unroll
      for (int j = 0; j < 4; ++j)
#pragma unroll
        for (int r = 0; r < 4; ++r)
          C[(size_t)(rbase + r) * ldc + cbase + j * 16] = f2bf(acc[i][j][r] + bv[j]);
    }
  }
}

// vt[b][d][s] = v[b][s][d]  (64x64 LDS tile transpose, strided input)
__global__ __launch_bounds__(256) void transpose_kernel(const unsigned short* __restrict__ v,
                                                        int lda, long sV,
                                                        unsigned short* __restrict__ vt) {
  __shared__ unsigned short t[64][65];
  int b = blockIdx.z;
  int s0 = blockIdx.x * 64;
  int d0 = blockIdx.y * 64;
  int tid = threadIdx.x;
  int rr = tid >> 3;          // 0..31
  int c8 = (tid & 7) * 8;     // 0..56
  const unsigned short* vb = v + (size_t)sV * b;
#pragma unroll
  for (int it = 0; it < 2; ++it) {
    int row = rr + it * 32;
    u16x8 val = *(const u16x8*)&vb[(size_t)(s0 + row) * lda + d0 + c8];
#pragma unroll
    for (int j = 0; j < 8; ++j) t[row][c8 + j] = val[j];
  }
  __syncthreads();
#pragma unroll
  for (int it = 0; it < 2; ++it) {
    int drow = rr + it * 32;
    u16x8 o;
#pragma unroll
    for (int j = 0; j < 8; ++j) o[j] = t[c8 + j][drow];
    *(u16x8*)&vt[((size_t)b * DM + d0 + drow) * SEQ + s0 + c8] = o;
  }
}

// row softmax over SEQ f32 -> bf16 probs. one block per row (all batches flat).
__global__ __launch_bounds__(256) void softmax_kernel(const float* __restrict__ Sc,
                                                      unsigned short* __restrict__ P) {
  int row = blockIdx.x;
  int tid = threadIdx.x;
  const float* sr = Sc + (size_t)row * SEQ;
  float v[8];
  f32x4v a = ((const f32x4v*)sr)[tid * 2];
  f32x4v b = ((const f32x4v*)sr)[tid * 2 + 1];
  v[0]=a[0]; v[1]=a[1]; v[2]=a[2]; v[3]=a[3];
  v[4]=b[0]; v[5]=b[1]; v[6]=b[2]; v[7]=b[3];
  float m = v[0];
#pragma unroll
  for (int j = 1; j < 8; ++j) m = fmaxf(m, v[j]);
#pragma unroll
  for (int off = 32; off; off >>= 1) m = fmaxf(m, __shfl_xor(m, off));
  __shared__ float red[8];
  int wv = tid >> 6;
  if ((tid & 63) == 0) red[wv] = m;
  __syncthreads();
  m = fmaxf(fmaxf(red[0], red[1]), fmaxf(red[2], red[3]));
  float s = 0.f;
#pragma unroll
  for (int j = 0; j < 8; ++j) { v[j] = __expf(v[j] - m); s += v[j]; }
#pragma unroll
  for (int off = 32; off; off >>= 1) s += __shfl_xor(s, off);
  if ((tid & 63) == 0) red[4 + wv] = s;
  __syncthreads();
  s = red[4] + red[5] + red[6] + red[7];
  float inv = 1.f / s;
  u16x8 o;
#pragma unroll
  for (int j = 0; j < 8; ++j) o[j] = f2bf(v[j] * inv);
  *(u16x8*)&P[(size_t)row * SEQ + tid * 8] = o;
}

// y = LN(x + res(masked)) * g + b. x from f32 (xf) or bf16 (xb); out f32 or bf16.
__global__ __launch_bounds__(256) void ln_kernel(
    const float* __restrict__ xf, const unsigned short* __restrict__ xb,
    const unsigned short* __restrict__ res, int masked,
    const float* __restrict__ g, const float* __restrict__ be,
    float* __restrict__ outf, unsigned short* __restrict__ outb)
{
  int row = blockIdx.x;
  int s = row & (SEQ - 1);
  int tid = threadIdx.x;
  int d0 = tid * 4;
  float v[4];
  if (xf) {
    f32x4v t = ((const f32x4v*)(xf + (size_t)row * DM))[tid];
    v[0]=t[0]; v[1]=t[1]; v[2]=t[2]; v[3]=t[3];
  } else {
    u16x4 t = ((const u16x4*)(xb + (size_t)row * DM))[tid];
    v[0]=bf2f(t[0]); v[1]=bf2f(t[1]); v[2]=bf2f(t[2]); v[3]=bf2f(t[3]);
  }
  u16x4 rv = ((const u16x4*)(res + (size_t)row * DM))[tid];
#pragma unroll
  for (int j = 0; j < 4; ++j) {
    float r = bf2f(rv[j]);
    if (masked && (d0 + j) > s) r = 0.f;  // tril on attention OUTPUT: keep d<=s
    v[j] += r;
  }
  float s1 = v[0] + v[1] + v[2] + v[3];
  float s2 = v[0]*v[0] + v[1]*v[1] + v[2]*v[2] + v[3]*v[3];
#pragma unroll
  for (int off = 32; off; off >>= 1) { s1 += __shfl_xor(s1, off); s2 += __shfl_xor(s2, off); }
  __shared__ float red[8];
  int wv = tid >> 6;
  if ((tid & 63) == 0) { red[wv] = s1; red[4 + wv] = s2; }
  __syncthreads();
  s1 = red[0] + red[1] + red[2] + red[3];
  s2 = red[4] + red[5] + red[6] + red[7];
  float mean = s1 * (1.f / DM);
  float var = s2 * (1.f / DM) - mean * mean;
  float rstd = rsqrtf(var + 1e-5f);
  f32x4v gv = ((const f32x4v*)g)[tid];
  f32x4v bv = ((const f32x4v*)be)[tid];
  if (outf) {
    f32x4v o;
#pragma unroll
    for (int j = 0; j < 4; ++j) o[j] = (v[j] - mean) * rstd * gv[j] + bv[j];
    ((f32x4v*)(outf + (size_t)row * DM))[tid] = o;
  } else {
    u16x4 o;
#pragma unroll
    for (int j = 0; j < 4; ++j) o[j] = f2bf((v[j] - mean) * rstd * gv[j] + bv[j]);
    ((u16x4*)(outb + (size_t)row * DM))[tid] = o;
  }
}

extern "C" void kernel_launch(void* const* d_in, const int* in_sizes, int n_in,
                              void* d_out, int out_size, void* d_ws, size_t ws_size,
                              hipStream_t stream) {
  (void)in_sizes; (void)n_in; (void)out_size; (void)ws_size;
  const float* x     = (const float*)d_in[0];
  const float* wq_w  = (const float*)d_in[1];
  const float* wq_b  = (const float*)d_in[2];
  const float* wk_w  = (const float*)d_in[3];
  const float* wk_b  = (const float*)d_in[4];
  const float* wv_w  = (const float*)d_in[5];
  const float* wv_b  = (const float*)d_in[6];
  const float* lin_w = (const float*)d_in[7];
  const float* lin_b = (const float*)d_in[8];
  const float* g1    = (const float*)d_in[9];
  const float* b1    = (const float*)d_in[10];
  const float* g2    = (const float*)d_in[11];
  const float* b2    = (const float*)d_in[12];

  const size_t MB = 1ull << 20;
  char* ws = (char*)d_ws;
  // ---- workspace layout with liveness overlays (peak ~163 MB) ----
  // [0,64)    sc: scores f32 [NB][SEQ][SEQ]        (written by QK^T, dead after softmax)
  //   [0,16)  attn overlays sc (PV output, after softmax)
  //   [16,32) lin  overlays sc
  //   [32,48) x1   overlays sc
  //   [48,54) wqkvb (bf16 [3*DM][DM]) — dead after QKV GEMM, before sc written
  //   [54,70) xb (x bf16) — dead after QKV GEMM   (extends into P region, see below)
  // [64,96)   P: probs bf16 — written by softmax, AFTER xb is dead
  // [96,144)  qkv: [NB*SEQ][3*DM]
  // [144,160) vt: V^T [NB][DM][SEQ]
  // [160,162) lwb: lin_w bf16
  // [162,...) bqkv: f32[3072] concat bias  (disjoint from everything — R2 bug was placing this inside xb)
  float*          sc   = (float*)(ws);
  unsigned short* attn = (unsigned short*)(ws);
  unsigned short* lin  = (unsigned short*)(ws + 16*MB);
  unsigned short* x1   = (unsigned short*)(ws + 32*MB);
  unsigned short* wqkvb= (unsigned short*)(ws + 48*MB);
  unsigned short* xb   = (unsigned short*)(ws + 54*MB);
  unsigned short* P    = (unsigned short*)(ws + 64*MB);
  unsigned short* qkv  = (unsigned short*)(ws + 96*MB);
  unsigned short* vt   = (unsigned short*)(ws + 144*MB);
  unsigned short* lwb  = (unsigned short*)(ws + 160*MB);
  float*          bqkv = (float*)(ws + 162*MB);

  const size_t SD = (size_t)NB * SEQ * DM;

  // stage: conversions + bias concat
  cvt_kernel<<<2048, 256, 0, stream>>>(x, xb, (int)(SD / 4));
  cvt_kernel<<<1024, 256, 0, stream>>>(wq_w, wqkvb, DM * DM / 4);
  cvt_kernel<<<1024, 256, 0, stream>>>(wk_w, wqkvb + DM * DM, DM * DM / 4);
  cvt_kernel<<<1024, 256, 0, stream>>>(wv_w, wqkvb + 2 * DM * DM, DM * DM / 4);
  cvt_kernel<<<1024, 256, 0, stream>>>(lin_w, lwb, DM * DM / 4);
  hipMemcpyAsync(bqkv,        wq_b, DM * sizeof(float), hipMemcpyDeviceToDevice, stream);
  hipMemcpyAsync(bqkv + DM,   wk_b, DM * sizeof(float), hipMemcpyDeviceToDevice, stream);
  hipMemcpyAsync(bqkv + 2*DM, wv_b, DM * sizeof(float), hipMemcpyDeviceToDevice, stream);

  // fused QKV projection: [8192,3072] = xb * wqkv^T + bqkv  (1536 blocks)
  gemm_bt<<<dim3(64, 24, 1), 256, 0, stream>>>(xb, DM, 0, wqkvb, DM, 0, qkv, 3 * DM, 0,
                                               DM, bqkv, 1.f, 0);
  // V^T (V = qkv cols [2048,3072), row stride 3072)
  transpose_kernel<<<dim3(SEQ / 64, DM / 64, NB), 256, 0, stream>>>(
      qkv + 2 * DM, 3 * DM, (long)SEQ * 3 * DM, vt);

  const float scale = 0.03125f;  // 1/sqrt(1024)
  // scores = Q K^T * scale, batched over z
  gemm_bt<<<dim3(16, 16, NB), 256, 0, stream>>>(
      qkv, 3 * DM, (long)SEQ * 3 * DM,            // Q
      qkv + DM, 3 * DM, (long)SEQ * 3 * DM,       // K
      sc, SEQ, (long)SEQ * SEQ, DM, nullptr, scale, 1);
  softmax_kernel<<<NB * SEQ, 256, 0, stream>>>(sc, P);
  // attn = P * (V^T)^T, batched over z
  gemm_bt<<<dim3(16, 8, NB), 256, 0, stream>>>(
      P, SEQ, (long)SEQ * SEQ,
      vt, SEQ, (long)DM * SEQ,
      attn, DM, (long)SEQ * DM, SEQ, nullptr, 1.f, 0);

  // LN1(x + tril(attn)) -> x1 (bf16)
  ln_kernel<<<NB * SEQ, 256, 0, stream>>>(x, nullptr, attn, 1, g1, b1, nullptr, x1);
  // linear = x1 * lin_w^T + lin_b
  gemm_bt<<<dim3(64, 8, 1), 256, 0, stream>>>(x1, DM, 0, lwb, DM, 0, lin, DM, 0, DM, lin_b, 1.f, 0);
  // LN2(x1 + linear) -> d_out (f32)
  ln_kernel<<<NB * SEQ, 256, 0, stream>>>(nullptr, x1, lin, 0, g2, b2, (float*)d_out, nullptr);
}

// Round 4
// 235.218 us; speedup vs baseline: 1.5857x; 1.0021x over previous
//
#include <hip/hip_runtime.h>
#include <hip/hip_bf16.h>

#define SEQ 2048
#define DM 1024
#define NB 4

typedef short bf16x8 __attribute__((ext_vector_type(8)));
typedef float f32x4 __attribute__((ext_vector_type(4)));
typedef float f32x4v __attribute__((ext_vector_type(4)));
typedef unsigned short u16x4 __attribute__((ext_vector_type(4)));
typedef unsigned short u16x8 __attribute__((ext_vector_type(8)));

__device__ __forceinline__ float bf2f(unsigned short u) {
  union { unsigned int i; float f; } w; w.i = ((unsigned int)u) << 16; return w.f;
}
__device__ __forceinline__ unsigned short f2bf(float f) {
  union { __hip_bfloat16 h; unsigned short u; } w; w.h = __float2bfloat16(f); return w.u;
}
__device__ __forceinline__ void load_lds16(const void* g, void* l) {
  __builtin_amdgcn_global_load_lds((const __attribute__((address_space(1))) void*)g,
                                   (__attribute__((address_space(3))) void*)l, 16, 0, 0);
}

// f32 -> bf16 conversion (vectorized, grid-stride)
__global__ __launch_bounds__(256) void cvt_kernel(const float* __restrict__ in,
                                                  unsigned short* __restrict__ out, int n4) {
  int idx = blockIdx.x * 256 + threadIdx.x;
  int stride = gridDim.x * 256;
  for (int i = idx; i < n4; i += stride) {
    f32x4v x = ((const f32x4v*)in)[i];
    u16x4 o;
    o[0] = f2bf(x[0]); o[1] = f2bf(x[1]); o[2] = f2bf(x[2]); o[3] = f2bf(x[3]);
    ((u16x4*)out)[i] = o;
  }
}

// ---------------- 128x128 / BK=64 / 4-wave GEMM (m97 structure) ----------------
// C = A * B^T (+bias) (*scale). trilskip: skip blocks fully above output diagonal.
__global__ __launch_bounds__(256, 2) void gemm_bt(
    const unsigned short* __restrict__ A, int lda, long sA,
    const unsigned short* __restrict__ B, int ldb, long sB,
    void* __restrict__ Cv, int ldc, long sC,
    int K, const float* __restrict__ bias, float scale, int outf32, int trilskip)
{
  const int m0 = blockIdx.x * 128, n0 = blockIdx.y * 128;
  if (trilskip && n0 > m0 + 127) return;  // output cols all > rows: fully masked later
  __shared__ unsigned short As[128 * 64];
  __shared__ unsigned short Bs[128 * 64];
  const int tid = threadIdx.x;
  const int lane = tid & 63;
  const int wave = tid >> 6;
  const int wm = wave >> 1, wn = wave & 1;
  const unsigned short* Ab = A + (size_t)sA * blockIdx.z;
  const unsigned short* Bb = B + (size_t)sB * blockIdx.z;

  f32x4 acc[4][4];
#pragma unroll
  for (int i = 0; i < 4; ++i)
#pragma unroll
    for (int j = 0; j < 4; ++j)
      acc[i][j] = (f32x4){0.f, 0.f, 0.f, 0.f};

  const int nk = K >> 6;
  for (int kt = 0; kt < nk; ++kt) {
    __syncthreads();
    const int kb = kt << 6;
#pragma unroll
    for (int it = 0; it < 4; ++it) {
      int c = it * 256 + tid;
      int row = c >> 3;
      int lslot = (c & 7) ^ (row & 7);
      int ldsoff = (it * 256 + wave * 64) * 8;
      load_lds16(Ab + (size_t)(m0 + row) * lda + kb + lslot * 8, &As[ldsoff]);
      load_lds16(Bb + (size_t)(n0 + row) * ldb + kb + lslot * 8, &Bs[ldsoff]);
    }
    __syncthreads();
#pragma unroll
    for (int h = 0; h < 2; ++h) {
      bf16x8 af[4], bfr[4];
#pragma unroll
      for (int i = 0; i < 4; ++i) {
        int row = wm * 64 + i * 16 + (lane & 15);
        int pslot = (h * 4 + (lane >> 4)) ^ (row & 7);
        af[i] = *(const bf16x8*)&As[row * 64 + pslot * 8];
      }
#pragma unroll
      for (int j = 0; j < 4; ++j) {
        int row = wn * 64 + j * 16 + (lane & 15);
        int pslot = (h * 4 + (lane >> 4)) ^ (row & 7);
        bfr[j] = *(const bf16x8*)&Bs[row * 64 + pslot * 8];
      }
#pragma unroll
      for (int i = 0; i < 4; ++i)
#pragma unroll
        for (int j = 0; j < 4; ++j)
          acc[i][j] = __builtin_amdgcn_mfma_f32_16x16x32_bf16(af[i], bfr[j], acc[i][j], 0, 0, 0);
    }
  }

  const int rsub = (lane >> 4) * 4;
  const int cbase = n0 + wn * 64 + (lane & 15);
  if (outf32) {
    float* C = (float*)Cv + (size_t)sC * blockIdx.z;
#pragma unroll
    for (int i = 0; i < 4; ++i) {
      int rbase = m0 + wm * 64 + i * 16 + rsub;
#pragma unroll
      for (int j = 0; j < 4; ++j)
#pragma unroll
        for (int r = 0; r < 4; ++r)
          C[(size_t)(rbase + r) * ldc + cbase + j * 16] = acc[i][j][r] * scale;
    }
  } else {
    unsigned short* C = (unsigned short*)Cv + (size_t)sC * blockIdx.z;
    float bv[4] = {0.f, 0.f, 0.f, 0.f};
    if (bias) {
#pragma unroll
      for (int j = 0; j < 4; ++j) bv[j] = bias[cbase + j * 16];
    }
#pragma unroll
    for (int i = 0; i < 4; ++i) {
      int rbase = m0 + wm * 64 + i * 16 + rsub;
#pragma unroll
      for (int j = 0; j < 4; ++j)
#pragma unroll
        for (int r = 0; r < 4; ++r)
          C[(size_t)(rbase + r) * ldc + cbase + j * 16] = f2bf(acc[i][j][r] * scale + bv[j]);
    }
  }
}

// ---------------- 256x256 / BK=64 / 8-wave deep-pipelined GEMM ----------------
// Counted-vmcnt double-buffer: prefetch for tile kt+2 is issued BEFORE the wait
// for tile kt+1, so 8-16 global_load_lds stay in flight across barriers (T3/T4).
// Raw s_barrier + asm s_waitcnt vmcnt(8) + sched_barrier(0) pins; setprio on MFMA (T5).
// Best at grids that are a multiple of 256 blocks (1 block/CU, 128 KiB LDS).
__global__ __launch_bounds__(512, 2) void gemm256(
    const unsigned short* __restrict__ A, int lda, long sA,
    const unsigned short* __restrict__ B, int ldb, long sB,
    void* __restrict__ Cv, int ldc, long sC,
    int K, const float* __restrict__ bias, float scale, int outf32)
{
  __shared__ unsigned short As[2][256 * 64];
  __shared__ unsigned short Bs[2][256 * 64];
  const int tid = threadIdx.x;
  const int lane = tid & 63;
  const int wave = tid >> 6;     // 0..7
  const int wm = wave >> 2;      // 0..1 : +wm*128 rows
  const int wn = wave & 3;       // 0..3 : +wn*64 cols
  const int m0 = blockIdx.x * 256, n0 = blockIdx.y * 256;
  const unsigned short* Ab = A + (size_t)sA * blockIdx.z;
  const unsigned short* Bb = B + (size_t)sB * blockIdx.z;

  f32x4 acc[8][4];
#pragma unroll
  for (int i = 0; i < 8; ++i)
#pragma unroll
    for (int j = 0; j < 4; ++j)
      acc[i][j] = (f32x4){0.f, 0.f, 0.f, 0.f};

  const int nk = K >> 6;

  // stage K-tile kt into buffer b: per thread 4 chunks/operand, issue order A,B,A,B,...
  // (8 loads/thread/tile). LDS dest linear; global source column pre-swizzled.
  auto STAGE = [&](int b, int kt) {
    const int kb = kt << 6;
#pragma unroll
    for (int i = 0; i < 4; ++i) {
      int c = i * 512 + tid;
      int row = c >> 3;
      int lslot = (c & 7) ^ (row & 7);
      load_lds16(Ab + (size_t)(m0 + row) * lda + kb + lslot * 8, &As[b][c * 8]);
      load_lds16(Bb + (size_t)(n0 + row) * ldb + kb + lslot * 8, &Bs[b][c * 8]);
    }
  };

  STAGE(0, 0);
  if (nk > 1) {
    STAGE(1, 1);
    asm volatile("s_waitcnt vmcnt(8)" ::: "memory");  // buf0 landed; buf1 in flight
  } else {
    asm volatile("s_waitcnt vmcnt(0)" ::: "memory");
  }
  __builtin_amdgcn_sched_barrier(0);
  __builtin_amdgcn_s_barrier();
  __builtin_amdgcn_sched_barrier(0);

  for (int kt = 0; kt < nk; ++kt) {
    const int b = kt & 1;
    const unsigned short* Asb = As[b];
    const unsigned short* Bsb = Bs[b];
    // B fragments once per K-tile (shared by all 4 M-quadrants)
    bf16x8 bfr[4][2];
#pragma unroll
    for (int j = 0; j < 4; ++j) {
      int row = wn * 64 + j * 16 + (lane & 15);
#pragma unroll
      for (int h = 0; h < 2; ++h) {
        int pslot = (h * 4 + (lane >> 4)) ^ (row & 7);
        bfr[j][h] = *(const bf16x8*)&Bsb[row * 64 + pslot * 8];
      }
    }
    // 4 phases over M quadrants: {4 ds_read -> 16 MFMA} each
#pragma unroll
    for (int q = 0; q < 4; ++q) {
      bf16x8 af[2][2];
#pragma unroll
      for (int i = 0; i < 2; ++i) {
        int row = wm * 128 + (q * 2 + i) * 16 + (lane & 15);
#pragma unroll
        for (int h = 0; h < 2; ++h) {
          int pslot = (h * 4 + (lane >> 4)) ^ (row & 7);
          af[i][h] = *(const bf16x8*)&Asb[row * 64 + pslot * 8];
        }
      }
      __builtin_amdgcn_s_setprio(1);
#pragma unroll
      for (int i = 0; i < 2; ++i)
#pragma unroll
        for (int j = 0; j < 4; ++j)
#pragma unroll
          for (int h = 0; h < 2; ++h)
            acc[q * 2 + i][j] =
                __builtin_amdgcn_mfma_f32_16x16x32_bf16(af[i][h], bfr[j][h], acc[q * 2 + i][j], 0, 0, 0);
      __builtin_amdgcn_s_setprio(0);
    }
    __builtin_amdgcn_sched_barrier(0);
    __builtin_amdgcn_s_barrier();        // A: all waves done reading buf b
    __builtin_amdgcn_sched_barrier(0);
    if (kt + 2 < nk) STAGE(b, kt + 2);   // refill freed buffer (8 loads, no wait)
    if (kt + 1 < nk) {
      if (kt + 2 < nk) asm volatile("s_waitcnt vmcnt(8)" ::: "memory");  // kt+1 landed, kt+2 in flight
      else             asm volatile("s_waitcnt vmcnt(0)" ::: "memory");
      __builtin_amdgcn_sched_barrier(0);
      __builtin_amdgcn_s_barrier();      // B: publish buf b^1
      __builtin_amdgcn_sched_barrier(0);
    }
  }

  // epilogue: wave tile 128x64; frag (mi,j): row = m0+wm*128+mi*16+(lane>>4)*4+r, col = n0+wn*64+j*16+(lane&15)
  const int rsub = (lane >> 4) * 4;
  const int cbase = n0 + wn * 64 + (lane & 15);
  if (outf32) {
    float* C = (float*)Cv + (size_t)sC * blockIdx.z;
#pragma unroll
    for (int i = 0; i < 8; ++i) {
      int rbase = m0 + wm * 128 + i * 16 + rsub;
#pragma unroll
      for (int j = 0; j < 4; ++j)
#pragma unroll
        for (int r = 0; r < 4; ++r)
          C[(size_t)(rbase + r) * ldc + cbase + j * 16] = acc[i][j][r] * scale;
    }
  } else {
    unsigned short* C = (unsigned short*)Cv + (size_t)sC * blockIdx.z;
    float bv[4] = {0.f, 0.f, 0.f, 0.f};
    if (bias) {
#pragma unroll
      for (int j = 0; j < 4; ++j) bv[j] = bias[cbase + j * 16];
    }
#pragma unroll
    for (int i = 0; i < 8; ++i) {
      int rbase = m0 + wm * 128 + i * 16 + rsub;
#pragma unroll
      for (int j = 0; j < 4; ++j)
#pragma unroll
        for (int r = 0; r < 4; ++r)
          C[(size_t)(rbase + r) * ldc + cbase + j * 16] = f2bf(acc[i][j][r] * scale + bv[j]);
    }
  }
}

// vt[b][d][s] = v[b][s][d]  (64x64 LDS tile transpose, strided input)
__global__ __launch_bounds__(256) void transpose_kernel(const unsigned short* __restrict__ v,
                                                        int lda, long sV,
                                                        unsigned short* __restrict__ vt) {
  __shared__ unsigned short t[64][65];
  int b = blockIdx.z;
  int s0 = blockIdx.x * 64;
  int d0 = blockIdx.y * 64;
  int tid = threadIdx.x;
  int rr = tid >> 3;
  int c8 = (tid & 7) * 8;
  const unsigned short* vb = v + (size_t)sV * b;
#pragma unroll
  for (int it = 0; it < 2; ++it) {
    int row = rr + it * 32;
    u16x8 val = *(const u16x8*)&vb[(size_t)(s0 + row) * lda + d0 + c8];
#pragma unroll
    for (int j = 0; j < 8; ++j) t[row][c8 + j] = val[j];
  }
  __syncthreads();
#pragma unroll
  for (int it = 0; it < 2; ++it) {
    int drow = rr + it * 32;
    u16x8 o;
#pragma unroll
    for (int j = 0; j < 8; ++j) o[j] = t[c8 + j][drow];
    *(u16x8*)&vt[((size_t)b * DM + d0 + drow) * SEQ + s0 + c8] = o;
  }
}

// in-place row softmax over SEQ bf16 -> bf16 probs. one block per row.
__global__ __launch_bounds__(256) void softmax_kernel(unsigned short* __restrict__ Sc) {
  int row = blockIdx.x;
  int tid = threadIdx.x;
  unsigned short* sr = Sc + (size_t)row * SEQ;
  u16x8 raw = *(const u16x8*)&sr[tid * 8];
  float v[8];
#pragma unroll
  for (int j = 0; j < 8; ++j) v[j] = bf2f(raw[j]);
  float m = v[0];
#pragma unroll
  for (int j = 1; j < 8; ++j) m = fmaxf(m, v[j]);
#pragma unroll
  for (int off = 32; off; off >>= 1) m = fmaxf(m, __shfl_xor(m, off));
  __shared__ float red[8];
  int wv = tid >> 6;
  if ((tid & 63) == 0) red[wv] = m;
  __syncthreads();
  m = fmaxf(fmaxf(red[0], red[1]), fmaxf(red[2], red[3]));
  float s = 0.f;
#pragma unroll
  for (int j = 0; j < 8; ++j) { v[j] = __expf(v[j] - m); s += v[j]; }
#pragma unroll
  for (int off = 32; off; off >>= 1) s += __shfl_xor(s, off);
  if ((tid & 63) == 0) red[4 + wv] = s;
  __syncthreads();
  s = red[4] + red[5] + red[6] + red[7];
  float inv = 1.f / s;
  u16x8 o;
#pragma unroll
  for (int j = 0; j < 8; ++j) o[j] = f2bf(v[j] * inv);
  *(u16x8*)&sr[tid * 8] = o;
}

// y = LN(x + res(masked)) * g + b. x from f32 (xf) or bf16 (xb); out f32 or bf16.
__global__ __launch_bounds__(256) void ln_kernel(
    const float* __restrict__ xf, const unsigned short* __restrict__ xb,
    const unsigned short* __restrict__ res, int masked,
    const float* __restrict__ g, const float* __restrict__ be,
    float* __restrict__ outf, unsigned short* __restrict__ outb)
{
  int row = blockIdx.x;
  int s = row & (SEQ - 1);
  int tid = threadIdx.x;
  int d0 = tid * 4;
  float v[4];
  if (xf) {
    f32x4v t = ((const f32x4v*)(xf + (size_t)row * DM))[tid];
    v[0]=t[0]; v[1]=t[1]; v[2]=t[2]; v[3]=t[3];
  } else {
    u16x4 t = ((const u16x4*)(xb + (size_t)row * DM))[tid];
    v[0]=bf2f(t[0]); v[1]=bf2f(t[1]); v[2]=bf2f(t[2]); v[3]=bf2f(t[3]);
  }
  u16x4 rv = ((const u16x4*)(res + (size_t)row * DM))[tid];
#pragma unroll
  for (int j = 0; j < 4; ++j) {
    float r = bf2f(rv[j]);
    if (masked && (d0 + j) > s) r = 0.f;
    v[j] += r;
  }
  float s1 = v[0] + v[1] + v[2] + v[3];
  float s2 = v[0]*v[0] + v[1]*v[1] + v[2]*v[2] + v[3]*v[3];
#pragma unroll
  for (int off = 32; off; off >>= 1) { s1 += __shfl_xor(s1, off); s2 += __shfl_xor(s2, off); }
  __shared__ float red[8];
  int wv = tid >> 6;
  if ((tid & 63) == 0) { red[wv] = s1; red[4 + wv] = s2; }
  __syncthreads();
  s1 = red[0] + red[1] + red[2] + red[3];
  s2 = red[4] + red[5] + red[6] + red[7];
  float mean = s1 * (1.f / DM);
  float var = s2 * (1.f / DM) - mean * mean;
  float rstd = rsqrtf(var + 1e-5f);
  f32x4v gv = ((const f32x4v*)g)[tid];
  f32x4v bv = ((const f32x4v*)be)[tid];
  if (outf) {
    f32x4v o;
#pragma unroll
    for (int j = 0; j < 4; ++j) o[j] = (v[j] - mean) * rstd * gv[j] + bv[j];
    ((f32x4v*)(outf + (size_t)row * DM))[tid] = o;
  } else {
    u16x4 o;
#pragma unroll
    for (int j = 0; j < 4; ++j) o[j] = f2bf((v[j] - mean) * rstd * gv[j] + bv[j]);
    ((u16x4*)(outb + (size_t)row * DM))[tid] = o;
  }
}

extern "C" void kernel_launch(void* const* d_in, const int* in_sizes, int n_in,
                              void* d_out, int out_size, void* d_ws, size_t ws_size,
                              hipStream_t stream) {
  (void)in_sizes; (void)n_in; (void)out_size; (void)ws_size;
  const float* x     = (const float*)d_in[0];
  const float* wq_w  = (const float*)d_in[1];
  const float* wq_b  = (const float*)d_in[2];
  const float* wk_w  = (const float*)d_in[3];
  const float* wk_b  = (const float*)d_in[4];
  const float* wv_w  = (const float*)d_in[5];
  const float* wv_b  = (const float*)d_in[6];
  const float* lin_w = (const float*)d_in[7];
  const float* lin_b = (const float*)d_in[8];
  const float* g1    = (const float*)d_in[9];
  const float* b1    = (const float*)d_in[10];
  const float* g2    = (const float*)d_in[11];
  const float* b2    = (const float*)d_in[12];

  const size_t MB = 1ull << 20;
  char* ws = (char*)d_ws;
  // ---- workspace layout: NO overlays (peak 176 MiB) ----
  unsigned short* scP  = (unsigned short*)(ws);            // [0,32)    scores/probs bf16, softmax in-place
  unsigned short* attn = (unsigned short*)(ws + 32*MB);    // [32,48)
  unsigned short* x1   = (unsigned short*)(ws + 48*MB);    // [48,64)
  unsigned short* lin  = (unsigned short*)(ws + 64*MB);    // [64,80)
  unsigned short* xb   = (unsigned short*)(ws + 80*MB);    // [80,96)
  unsigned short* wqkvb= (unsigned short*)(ws + 96*MB);    // [96,102)
  unsigned short* lwb  = (unsigned short*)(ws + 102*MB);   // [102,104)
  float*          bqkv = (float*)(ws + 104*MB);            // [104,+12KiB)
  unsigned short* qkv  = (unsigned short*)(ws + 112*MB);   // [112,160)
  unsigned short* vt   = (unsigned short*)(ws + 160*MB);   // [160,176)

  const size_t SD = (size_t)NB * SEQ * DM;

  cvt_kernel<<<2048, 256, 0, stream>>>(x, xb, (int)(SD / 4));
  cvt_kernel<<<1024, 256, 0, stream>>>(wq_w, wqkvb, DM * DM / 4);
  cvt_kernel<<<1024, 256, 0, stream>>>(wk_w, wqkvb + DM * DM, DM * DM / 4);
  cvt_kernel<<<1024, 256, 0, stream>>>(wv_w, wqkvb + 2 * DM * DM, DM * DM / 4);
  cvt_kernel<<<1024, 256, 0, stream>>>(lin_w, lwb, DM * DM / 4);
  hipMemcpyAsync(bqkv,        wq_b, DM * sizeof(float), hipMemcpyDeviceToDevice, stream);
  hipMemcpyAsync(bqkv + DM,   wk_b, DM * sizeof(float), hipMemcpyDeviceToDevice, stream);
  hipMemcpyAsync(bqkv + 2*DM, wv_b, DM * sizeof(float), hipMemcpyDeviceToDevice, stream);

  // fused QKV projection: [8192,3072] = xb * wqkv^T + bqkv  (1536 blocks, 2/CU)
  gemm_bt<<<dim3(64, 24, 1), 256, 0, stream>>>(xb, DM, 0, wqkvb, DM, 0, qkv, 3 * DM, 0,
                                               DM, bqkv, 1.f, 0, 0);
  transpose_kernel<<<dim3(SEQ / 64, DM / 64, NB), 256, 0, stream>>>(
      qkv + 2 * DM, 3 * DM, (long)SEQ * 3 * DM, vt);

  const float scale = 0.03125f;  // 1/sqrt(1024)
  // scores = (Q K^T) * scale -> bf16, batched: 8x8x4 = 256 blocks = 1 block/CU (gemm256 sweet spot)
  gemm256<<<dim3(8, 8, NB), 512, 0, stream>>>(
      qkv, 3 * DM, (long)SEQ * 3 * DM,
      qkv + DM, 3 * DM, (long)SEQ * 3 * DM,
      scP, SEQ, (long)SEQ * SEQ, DM, nullptr, scale, 0);
  softmax_kernel<<<NB * SEQ, 256, 0, stream>>>(scP);
  // attn = P * (V^T)^T with tril tile-skip (by > bx fully masked downstream)
  gemm_bt<<<dim3(16, 8, NB), 256, 0, stream>>>(
      scP, SEQ, (long)SEQ * SEQ,
      vt, SEQ, (long)DM * SEQ,
      attn, DM, (long)SEQ * DM, SEQ, nullptr, 1.f, 0, 1);

  ln_kernel<<<NB * SEQ, 256, 0, stream>>>(x, nullptr, attn, 1, g1, b1, nullptr, x1);
  gemm_bt<<<dim3(64, 8, 1), 256, 0, stream>>>(x1, DM, 0, lwb, DM, 0, lin, DM, 0, DM, lin_b, 1.f, 0, 0);
  ln_kernel<<<NB * SEQ, 256, 0, stream>>>(nullptr, x1, lin, 0, g2, b2, (float*)d_out, nullptr);
}

// Round 5
// 224.362 us; speedup vs baseline: 1.6624x; 1.0484x over previous
//
#include <hip/hip_runtime.h>
#include <hip/hip_bf16.h>

#define SEQ 2048
#define DM 1024
#define NB 4

typedef short bf16x8 __attribute__((ext_vector_type(8)));
typedef float f32x4 __attribute__((ext_vector_type(4)));
typedef float f32x4v __attribute__((ext_vector_type(4)));
typedef unsigned short u16x4 __attribute__((ext_vector_type(4)));
typedef unsigned short u16x8 __attribute__((ext_vector_type(8)));

__device__ __forceinline__ float bf2f(unsigned short u) {
  union { unsigned int i; float f; } w; w.i = ((unsigned int)u) << 16; return w.f;
}
__device__ __forceinline__ unsigned short f2bf(float f) {
  union { __hip_bfloat16 h; unsigned short u; } w; w.h = __float2bfloat16(f); return w.u;
}
__device__ __forceinline__ void load_lds16(const void* g, void* l) {
  __builtin_amdgcn_global_load_lds((const __attribute__((address_space(1))) void*)g,
                                   (__attribute__((address_space(3))) void*)l, 16, 0, 0);
}
__device__ __forceinline__ void cvt4(const float* __restrict__ in,
                                     unsigned short* __restrict__ out, int i) {
  f32x4v v = ((const f32x4v*)in)[i];
  u16x4 o;
  o[0] = f2bf(v[0]); o[1] = f2bf(v[1]); o[2] = f2bf(v[2]); o[3] = f2bf(v[3]);
  ((u16x4*)out)[i] = o;
}

// One fused staging pass: x->xb, {wq,wk,wv}->wqkvb, lin_w->lwb, biases->bqkv (f32 concat).
__global__ __launch_bounds__(256) void stage_kernel(
    const float* __restrict__ x,
    const float* __restrict__ wq, const float* __restrict__ wk,
    const float* __restrict__ wv, const float* __restrict__ lw,
    const float* __restrict__ bq, const float* __restrict__ bk, const float* __restrict__ bv,
    unsigned short* __restrict__ xb, unsigned short* __restrict__ wqkvb,
    unsigned short* __restrict__ lwb, float* __restrict__ bqkv)
{
  const int XC = (NB * SEQ * DM) / 4;   // 2097152 chunks
  const int WC = (DM * DM) / 4;         // 262144
  const int BC = (3 * DM) / 4;          // 768
  const int total = XC + 4 * WC + BC;
  int idx = blockIdx.x * 256 + threadIdx.x;
  int stride = gridDim.x * 256;
  for (int i = idx; i < total; i += stride) {
    if (i < XC) { cvt4(x, xb, i); continue; }
    int j = i - XC;
    if (j < WC)          { cvt4(wq, wqkvb, j); continue; }
    if (j < 2 * WC)      { cvt4(wk, wqkvb + (size_t)DM * DM, j - WC); continue; }
    if (j < 3 * WC)      { cvt4(wv, wqkvb + 2 * (size_t)DM * DM, j - 2 * WC); continue; }
    if (j < 4 * WC)      { cvt4(lw, lwb, j - 3 * WC); continue; }
    int c = j - 4 * WC;  // bias chunk, 0..767
    const float* src = (c < 256) ? bq : ((c < 512) ? bk : bv);
    int off = (c < 256) ? c : ((c < 512) ? c - 256 : c - 512);
    ((f32x4v*)bqkv)[c] = ((const f32x4v*)src)[off];
  }
}

// ---------------- 128x128 / BK=64 / 4-wave GEMM (m97 structure) ----------------
// C = A * B^T (+bias) (*scale). trilskip: skip blocks fully above output diagonal.
__global__ __launch_bounds__(256, 2) void gemm_bt(
    const unsigned short* __restrict__ A, int lda, long sA,
    const unsigned short* __restrict__ B, int ldb, long sB,
    void* __restrict__ Cv, int ldc, long sC,
    int K, const float* __restrict__ bias, float scale, int outf32, int trilskip)
{
  const int m0 = blockIdx.x * 128, n0 = blockIdx.y * 128;
  if (trilskip && n0 > m0 + 127) return;  // fully masked downstream
  __shared__ unsigned short As[128 * 64];
  __shared__ unsigned short Bs[128 * 64];
  const int tid = threadIdx.x;
  const int lane = tid & 63;
  const int wave = tid >> 6;
  const int wm = wave >> 1, wn = wave & 1;
  const unsigned short* Ab = A + (size_t)sA * blockIdx.z;
  const unsigned short* Bb = B + (size_t)sB * blockIdx.z;

  f32x4 acc[4][4];
#pragma unroll
  for (int i = 0; i < 4; ++i)
#pragma unroll
    for (int j = 0; j < 4; ++j)
      acc[i][j] = (f32x4){0.f, 0.f, 0.f, 0.f};

  const int nk = K >> 6;
  for (int kt = 0; kt < nk; ++kt) {
    __syncthreads();
    const int kb = kt << 6;
#pragma unroll
    for (int it = 0; it < 4; ++it) {
      int c = it * 256 + tid;
      int row = c >> 3;
      int lslot = (c & 7) ^ (row & 7);
      int ldsoff = (it * 256 + wave * 64) * 8;
      load_lds16(Ab + (size_t)(m0 + row) * lda + kb + lslot * 8, &As[ldsoff]);
      load_lds16(Bb + (size_t)(n0 + row) * ldb + kb + lslot * 8, &Bs[ldsoff]);
    }
    __syncthreads();
#pragma unroll
    for (int h = 0; h < 2; ++h) {
      bf16x8 af[4], bfr[4];
#pragma unroll
      for (int i = 0; i < 4; ++i) {
        int row = wm * 64 + i * 16 + (lane & 15);
        int pslot = (h * 4 + (lane >> 4)) ^ (row & 7);
        af[i] = *(const bf16x8*)&As[row * 64 + pslot * 8];
      }
#pragma unroll
      for (int j = 0; j < 4; ++j) {
        int row = wn * 64 + j * 16 + (lane & 15);
        int pslot = (h * 4 + (lane >> 4)) ^ (row & 7);
        bfr[j] = *(const bf16x8*)&Bs[row * 64 + pslot * 8];
      }
#pragma unroll
      for (int i = 0; i < 4; ++i)
#pragma unroll
        for (int j = 0; j < 4; ++j)
          acc[i][j] = __builtin_amdgcn_mfma_f32_16x16x32_bf16(af[i], bfr[j], acc[i][j], 0, 0, 0);
    }
  }

  const int rsub = (lane >> 4) * 4;
  const int cbase = n0 + wn * 64 + (lane & 15);
  if (outf32) {
    float* C = (float*)Cv + (size_t)sC * blockIdx.z;
#pragma unroll
    for (int i = 0; i < 4; ++i) {
      int rbase = m0 + wm * 64 + i * 16 + rsub;
#pragma unroll
      for (int j = 0; j < 4; ++j)
#pragma unroll
        for (int r = 0; r < 4; ++r)
          C[(size_t)(rbase + r) * ldc + cbase + j * 16] = acc[i][j][r] * scale;
    }
  } else {
    unsigned short* C = (unsigned short*)Cv + (size_t)sC * blockIdx.z;
    float bv[4] = {0.f, 0.f, 0.f, 0.f};
    if (bias) {
#pragma unroll
      for (int j = 0; j < 4; ++j) bv[j] = bias[cbase + j * 16];
    }
#pragma unroll
    for (int i = 0; i < 4; ++i) {
      int rbase = m0 + wm * 64 + i * 16 + rsub;
#pragma unroll
      for (int j = 0; j < 4; ++j)
#pragma unroll
        for (int r = 0; r < 4; ++r)
          C[(size_t)(rbase + r) * ldc + cbase + j * 16] = f2bf(acc[i][j][r] * scale + bv[j]);
    }
  }
}

// ---------------- 256x256 / BK=64 / 8-wave deep-pipelined GEMM ----------------
// Counted-vmcnt double-buffer (validated R4: QK^T correct). Optional epilogue mode:
// blocks with n0 >= vtBase write their output TRANSPOSED into vtOut[NB][DM][SEQ]
// (used to produce V^T directly from the QKV projection; qkv V-columns left unwritten).
__global__ __launch_bounds__(512, 2) void gemm256(
    const unsigned short* __restrict__ A, int lda, long sA,
    const unsigned short* __restrict__ B, int ldb, long sB,
    void* __restrict__ Cv, int ldc, long sC,
    int K, const float* __restrict__ bias, float scale, int outf32,
    unsigned short* __restrict__ vtOut, int vtBase)
{
  __shared__ unsigned short As[2][256 * 64];
  __shared__ unsigned short Bs[2][256 * 64];
  const int tid = threadIdx.x;
  const int lane = tid & 63;
  const int wave = tid >> 6;     // 0..7
  const int wm = wave >> 2;      // 0..1
  const int wn = wave & 3;       // 0..3
  const int m0 = blockIdx.x * 256, n0 = blockIdx.y * 256;
  const unsigned short* Ab = A + (size_t)sA * blockIdx.z;
  const unsigned short* Bb = B + (size_t)sB * blockIdx.z;

  f32x4 acc[8][4];
#pragma unroll
  for (int i = 0; i < 8; ++i)
#pragma unroll
    for (int j = 0; j < 4; ++j)
      acc[i][j] = (f32x4){0.f, 0.f, 0.f, 0.f};

  const int nk = K >> 6;

  auto STAGE = [&](int b, int kt) {
    const int kb = kt << 6;
#pragma unroll
    for (int i = 0; i < 4; ++i) {
      int c = i * 512 + tid;
      int row = c >> 3;
      int lslot = (c & 7) ^ (row & 7);
      load_lds16(Ab + (size_t)(m0 + row) * lda + kb + lslot * 8, &As[b][c * 8]);
      load_lds16(Bb + (size_t)(n0 + row) * ldb + kb + lslot * 8, &Bs[b][c * 8]);
    }
  };

  STAGE(0, 0);
  if (nk > 1) {
    STAGE(1, 1);
    asm volatile("s_waitcnt vmcnt(8)" ::: "memory");
  } else {
    asm volatile("s_waitcnt vmcnt(0)" ::: "memory");
  }
  __builtin_amdgcn_sched_barrier(0);
  __builtin_amdgcn_s_barrier();
  __builtin_amdgcn_sched_barrier(0);

  for (int kt = 0; kt < nk; ++kt) {
    const int b = kt & 1;
    const unsigned short* Asb = As[b];
    const unsigned short* Bsb = Bs[b];
    bf16x8 bfr[4][2];
#pragma unroll
    for (int j = 0; j < 4; ++j) {
      int row = wn * 64 + j * 16 + (lane & 15);
#pragma unroll
      for (int h = 0; h < 2; ++h) {
        int pslot = (h * 4 + (lane >> 4)) ^ (row & 7);
        bfr[j][h] = *(const bf16x8*)&Bsb[row * 64 + pslot * 8];
      }
    }
#pragma unroll
    for (int q = 0; q < 4; ++q) {
      bf16x8 af[2][2];
#pragma unroll
      for (int i = 0; i < 2; ++i) {
        int row = wm * 128 + (q * 2 + i) * 16 + (lane & 15);
#pragma unroll
        for (int h = 0; h < 2; ++h) {
          int pslot = (h * 4 + (lane >> 4)) ^ (row & 7);
          af[i][h] = *(const bf16x8*)&Asb[row * 64 + pslot * 8];
        }
      }
      __builtin_amdgcn_s_setprio(1);
#pragma unroll
      for (int i = 0; i < 2; ++i)
#pragma unroll
        for (int j = 0; j < 4; ++j)
#pragma unroll
          for (int h = 0; h < 2; ++h)
            acc[q * 2 + i][j] =
                __builtin_amdgcn_mfma_f32_16x16x32_bf16(af[i][h], bfr[j][h], acc[q * 2 + i][j], 0, 0, 0);
      __builtin_amdgcn_s_setprio(0);
    }
    __builtin_amdgcn_sched_barrier(0);
    __builtin_amdgcn_s_barrier();        // all waves done reading buf b
    __builtin_amdgcn_sched_barrier(0);
    if (kt + 2 < nk) STAGE(b, kt + 2);
    if (kt + 1 < nk) {
      if (kt + 2 < nk) asm volatile("s_waitcnt vmcnt(8)" ::: "memory");
      else             asm volatile("s_waitcnt vmcnt(0)" ::: "memory");
      __builtin_amdgcn_sched_barrier(0);
      __builtin_amdgcn_s_barrier();      // publish buf b^1
      __builtin_amdgcn_sched_barrier(0);
    }
  }

  const int rsub = (lane >> 4) * 4;
  const int cbase = n0 + wn * 64 + (lane & 15);
  if (vtOut && n0 >= vtBase) {
    // V^T path: out[s, col] -> vt[b][col-vtBase][s]; 4 consecutive s per reg quad = 8B store
    float bv[4] = {0.f, 0.f, 0.f, 0.f};
    if (bias) {
#pragma unroll
      for (int j = 0; j < 4; ++j) bv[j] = bias[cbase + j * 16];
    }
#pragma unroll
    for (int i = 0; i < 8; ++i) {
      int sg = m0 + wm * 128 + i * 16 + rsub;   // global row (batch*SEQ + s)
      int bb = sg >> 11;
      int sl = sg & (SEQ - 1);
#pragma unroll
      for (int j = 0; j < 4; ++j) {
        int d = cbase + j * 16 - vtBase;
        u16x4 o;
#pragma unroll
        for (int r = 0; r < 4; ++r) o[r] = f2bf(acc[i][j][r] * scale + bv[j]);
        *(u16x4*)&vtOut[((size_t)bb * DM + d) * SEQ + sl] = o;
      }
    }
  } else if (outf32) {
    float* C = (float*)Cv + (size_t)sC * blockIdx.z;
#pragma unroll
    for (int i = 0; i < 8; ++i) {
      int rbase = m0 + wm * 128 + i * 16 + rsub;
#pragma unroll
      for (int j = 0; j < 4; ++j)
#pragma unroll
        for (int r = 0; r < 4; ++r)
          C[(size_t)(rbase + r) * ldc + cbase + j * 16] = acc[i][j][r] * scale;
    }
  } else {
    unsigned short* C = (unsigned short*)Cv + (size_t)sC * blockIdx.z;
    float bv[4] = {0.f, 0.f, 0.f, 0.f};
    if (bias) {
#pragma unroll
      for (int j = 0; j < 4; ++j) bv[j] = bias[cbase + j * 16];
    }
#pragma unroll
    for (int i = 0; i < 8; ++i) {
      int rbase = m0 + wm * 128 + i * 16 + rsub;
#pragma unroll
      for (int j = 0; j < 4; ++j)
#pragma unroll
        for (int r = 0; r < 4; ++r)
          C[(size_t)(rbase + r) * ldc + cbase + j * 16] = f2bf(acc[i][j][r] * scale + bv[j]);
    }
  }
}

// in-place row softmax over SEQ bf16 -> bf16 probs. one block per row.
__global__ __launch_bounds__(256) void softmax_kernel(unsigned short* __restrict__ Sc) {
  int row = blockIdx.x;
  int tid = threadIdx.x;
  unsigned short* sr = Sc + (size_t)row * SEQ;
  u16x8 raw = *(const u16x8*)&sr[tid * 8];
  float v[8];
#pragma unroll
  for (int j = 0; j < 8; ++j) v[j] = bf2f(raw[j]);
  float m = v[0];
#pragma unroll
  for (int j = 1; j < 8; ++j) m = fmaxf(m, v[j]);
#pragma unroll
  for (int off = 32; off; off >>= 1) m = fmaxf(m, __shfl_xor(m, off));
  __shared__ float red[8];
  int wv = tid >> 6;
  if ((tid & 63) == 0) red[wv] = m;
  __syncthreads();
  m = fmaxf(fmaxf(red[0], red[1]), fmaxf(red[2], red[3]));
  float s = 0.f;
#pragma unroll
  for (int j = 0; j < 8; ++j) { v[j] = __expf(v[j] - m); s += v[j]; }
#pragma unroll
  for (int off = 32; off; off >>= 1) s += __shfl_xor(s, off);
  if ((tid & 63) == 0) red[4 + wv] = s;
  __syncthreads();
  s = red[4] + red[5] + red[6] + red[7];
  float inv = 1.f / s;
  u16x8 o;
#pragma unroll
  for (int j = 0; j < 8; ++j) o[j] = f2bf(v[j] * inv);
  *(u16x8*)&sr[tid * 8] = o;
}

// y = LN(x + res(masked)) * g + b. x from f32 (xf) or bf16 (xb); out f32 or bf16.
__global__ __launch_bounds__(256) void ln_kernel(
    const float* __restrict__ xf, const unsigned short* __restrict__ xb,
    const unsigned short* __restrict__ res, int masked,
    const float* __restrict__ g, const float* __restrict__ be,
    float* __restrict__ outf, unsigned short* __restrict__ outb)
{
  int row = blockIdx.x;
  int s = row & (SEQ - 1);
  int tid = threadIdx.x;
  int d0 = tid * 4;
  float v[4];
  if (xf) {
    f32x4v t = ((const f32x4v*)(xf + (size_t)row * DM))[tid];
    v[0]=t[0]; v[1]=t[1]; v[2]=t[2]; v[3]=t[3];
  } else {
    u16x4 t = ((const u16x4*)(xb + (size_t)row * DM))[tid];
    v[0]=bf2f(t[0]); v[1]=bf2f(t[1]); v[2]=bf2f(t[2]); v[3]=bf2f(t[3]);
  }
  u16x4 rv = ((const u16x4*)(res + (size_t)row * DM))[tid];
#pragma unroll
  for (int j = 0; j < 4; ++j) {
    float r = bf2f(rv[j]);
    if (masked && (d0 + j) > s) r = 0.f;
    v[j] += r;
  }
  float s1 = v[0] + v[1] + v[2] + v[3];
  float s2 = v[0]*v[0] + v[1]*v[1] + v[2]*v[2] + v[3]*v[3];
#pragma unroll
  for (int off = 32; off; off >>= 1) { s1 += __shfl_xor(s1, off); s2 += __shfl_xor(s2, off); }
  __shared__ float red[8];
  int wv = tid >> 6;
  if ((tid & 63) == 0) { red[wv] = s1; red[4 + wv] = s2; }
  __syncthreads();
  s1 = red[0] + red[1] + red[2] + red[3];
  s2 = red[4] + red[5] + red[6] + red[7];
  float mean = s1 * (1.f / DM);
  float var = s2 * (1.f / DM) - mean * mean;
  float rstd = rsqrtf(var + 1e-5f);
  f32x4v gv = ((const f32x4v*)g)[tid];
  f32x4v bv = ((const f32x4v*)be)[tid];
  if (outf) {
    f32x4v o;
#pragma unroll
    for (int j = 0; j < 4; ++j) o[j] = (v[j] - mean) * rstd * gv[j] + bv[j];
    ((f32x4v*)(outf + (size_t)row * DM))[tid] = o;
  } else {
    u16x4 o;
#pragma unroll
    for (int j = 0; j < 4; ++j) o[j] = f2bf((v[j] - mean) * rstd * gv[j] + bv[j]);
    ((u16x4*)(outb + (size_t)row * DM))[tid] = o;
  }
}

extern "C" void kernel_launch(void* const* d_in, const int* in_sizes, int n_in,
                              void* d_out, int out_size, void* d_ws, size_t ws_size,
                              hipStream_t stream) {
  (void)in_sizes; (void)n_in; (void)out_size; (void)ws_size;
  const float* x     = (const float*)d_in[0];
  const float* wq_w  = (const float*)d_in[1];
  const float* wq_b  = (const float*)d_in[2];
  const float* wk_w  = (const float*)d_in[3];
  const float* wk_b  = (const float*)d_in[4];
  const float* wv_w  = (const float*)d_in[5];
  const float* wv_b  = (const float*)d_in[6];
  const float* lin_w = (const float*)d_in[7];
  const float* lin_b = (const float*)d_in[8];
  const float* g1    = (const float*)d_in[9];
  const float* b1    = (const float*)d_in[10];
  const float* g2    = (const float*)d_in[11];
  const float* b2    = (const float*)d_in[12];

  const size_t MB = 1ull << 20;
  char* ws = (char*)d_ws;
  // ---- workspace layout: NO overlays (peak 176 MiB) ----
  unsigned short* scP  = (unsigned short*)(ws);            // [0,32)   scores/probs bf16, in-place softmax
  unsigned short* attn = (unsigned short*)(ws + 32*MB);    // [32,48)
  unsigned short* x1   = (unsigned short*)(ws + 48*MB);    // [48,64)
  unsigned short* lin  = (unsigned short*)(ws + 64*MB);    // [64,80)
  unsigned short* xb   = (unsigned short*)(ws + 80*MB);    // [80,96)
  unsigned short* wqkvb= (unsigned short*)(ws + 96*MB);    // [96,102)
  unsigned short* lwb  = (unsigned short*)(ws + 102*MB);   // [102,104)
  float*          bqkv = (float*)(ws + 104*MB);            // [104,+12KiB)
  unsigned short* qkv  = (unsigned short*)(ws + 112*MB);   // [112,160)  (V cols unwritten/unused)
  unsigned short* vt   = (unsigned short*)(ws + 160*MB);   // [160,176)  V^T [NB][DM][SEQ]

  // 1. fused staging (replaces 5 cvt + 3 memcpy)
  stage_kernel<<<2048, 256, 0, stream>>>(x, wq_w, wk_w, wv_w, lin_w, wq_b, wk_b, wv_b,
                                         xb, wqkvb, lwb, bqkv);

  // 2. fused QKV projection on gemm256 (32x12=384 blocks); V blocks (n0>=2048) write V^T directly
  gemm256<<<dim3(32, 12, 1), 512, 0, stream>>>(xb, DM, 0, wqkvb, DM, 0, qkv, 3 * DM, 0,
                                               DM, bqkv, 1.f, 0, vt, 2 * DM);

  const float scale = 0.03125f;  // 1/sqrt(1024)
  // 3. scores = (Q K^T) * scale -> bf16, batched: 8x8x4 = 256 blocks
  gemm256<<<dim3(8, 8, NB), 512, 0, stream>>>(
      qkv, 3 * DM, (long)SEQ * 3 * DM,
      qkv + DM, 3 * DM, (long)SEQ * 3 * DM,
      scP, SEQ, (long)SEQ * SEQ, DM, nullptr, scale, 0, nullptr, 0);
  // 4. softmax in-place
  softmax_kernel<<<NB * SEQ, 256, 0, stream>>>(scP);
  // 5. attn = P * (V^T)^T with tril tile-skip
  gemm_bt<<<dim3(16, 8, NB), 256, 0, stream>>>(
      scP, SEQ, (long)SEQ * SEQ,
      vt, SEQ, (long)DM * SEQ,
      attn, DM, (long)SEQ * DM, SEQ, nullptr, 1.f, 0, 1);

  // 6. LN1(xb + tril(attn)) -> x1 (bf16)
  ln_kernel<<<NB * SEQ, 256, 0, stream>>>(nullptr, xb, attn, 1, g1, b1, nullptr, x1);
  // 7. linear = x1 * lin_w^T + lin_b  (512 blocks, 2/CU)
  gemm_bt<<<dim3(64, 8, 1), 256, 0, stream>>>(x1, DM, 0, lwb, DM, 0, lin, DM, 0, DM, lin_b, 1.f, 0, 0);
  // 8. LN2(x1 + linear) -> d_out (f32)
  ln_kernel<<<NB * SEQ, 256, 0, stream>>>(nullptr, x1, lin, 0, g2, b2, (float*)d_out, nullptr);
}

// Round 6
// 208.738 us; speedup vs baseline: 1.7868x; 1.0749x over previous
//
#include <hip/hip_runtime.h>
#include <hip/hip_bf16.h>

#define SEQ 2048
#define DM 1024
#define NB 4

typedef short bf16x8 __attribute__((ext_vector_type(8)));
typedef float f32x4 __attribute__((ext_vector_type(4)));
typedef float f32x4v __attribute__((ext_vector_type(4)));
typedef unsigned short u16x4 __attribute__((ext_vector_type(4)));
typedef unsigned short u16x8 __attribute__((ext_vector_type(8)));

__device__ __forceinline__ float bf2f(unsigned short u) {
  union { unsigned int i; float f; } w; w.i = ((unsigned int)u) << 16; return w.f;
}
__device__ __forceinline__ unsigned short f2bf(float f) {
  union { __hip_bfloat16 h; unsigned short u; } w; w.h = __float2bfloat16(f); return w.u;
}
__device__ __forceinline__ void load_lds16(const void* g, void* l) {
  __builtin_amdgcn_global_load_lds((const __attribute__((address_space(1))) void*)g,
                                   (__attribute__((address_space(3))) void*)l, 16, 0, 0);
}
__device__ __forceinline__ void cvt4(const float* __restrict__ in,
                                     unsigned short* __restrict__ out, int i) {
  f32x4v v = ((const f32x4v*)in)[i];
  u16x4 o;
  o[0] = f2bf(v[0]); o[1] = f2bf(v[1]); o[2] = f2bf(v[2]); o[3] = f2bf(v[3]);
  ((u16x4*)out)[i] = o;
}

// One fused staging pass: x->xb, {wq,wk,wv}->wqkvb, lin_w->lwb, biases->bqkv (f32 concat).
__global__ __launch_bounds__(256) void stage_kernel(
    const float* __restrict__ x,
    const float* __restrict__ wq, const float* __restrict__ wk,
    const float* __restrict__ wv, const float* __restrict__ lw,
    const float* __restrict__ bq, const float* __restrict__ bk, const float* __restrict__ bv,
    unsigned short* __restrict__ xb, unsigned short* __restrict__ wqkvb,
    unsigned short* __restrict__ lwb, float* __restrict__ bqkv)
{
  const int XC = (NB * SEQ * DM) / 4;
  const int WC = (DM * DM) / 4;
  const int BC = (3 * DM) / 4;
  const int total = XC + 4 * WC + BC;
  int idx = blockIdx.x * 256 + threadIdx.x;
  int stride = gridDim.x * 256;
  for (int i = idx; i < total; i += stride) {
    if (i < XC) { cvt4(x, xb, i); continue; }
    int j = i - XC;
    if (j < WC)          { cvt4(wq, wqkvb, j); continue; }
    if (j < 2 * WC)      { cvt4(wk, wqkvb + (size_t)DM * DM, j - WC); continue; }
    if (j < 3 * WC)      { cvt4(wv, wqkvb + 2 * (size_t)DM * DM, j - 2 * WC); continue; }
    if (j < 4 * WC)      { cvt4(lw, lwb, j - 3 * WC); continue; }
    int c = j - 4 * WC;
    const float* src = (c < 256) ? bq : ((c < 512) ? bk : bv);
    int off = (c < 256) ? c : ((c < 512) ? c - 256 : c - 512);
    ((f32x4v*)bqkv)[c] = ((const f32x4v*)src)[off];
  }
}

// ---------------- 128x128 / BK=64 / 4-wave GEMM (m97 structure, measured ~950 TF) ----
// C = A * B^T (+bias) (*scale).
// trilskip: skip blocks fully above output diagonal (masked downstream).
// vtOut/vtBase: blocks with n0 >= vtBase write output TRANSPOSED into
// vtOut[NB][DM][SEQ] instead of C (fuses the V^T transpose into the QKV epilogue).
__global__ __launch_bounds__(256, 2) void gemm_bt(
    const unsigned short* __restrict__ A, int lda, long sA,
    const unsigned short* __restrict__ B, int ldb, long sB,
    void* __restrict__ Cv, int ldc, long sC,
    int K, const float* __restrict__ bias, float scale, int outf32, int trilskip,
    unsigned short* __restrict__ vtOut, int vtBase)
{
  const int m0 = blockIdx.x * 128, n0 = blockIdx.y * 128;
  if (trilskip && n0 > m0 + 127) return;
  __shared__ unsigned short As[128 * 64];
  __shared__ unsigned short Bs[128 * 64];
  const int tid = threadIdx.x;
  const int lane = tid & 63;
  const int wave = tid >> 6;
  const int wm = wave >> 1, wn = wave & 1;
  const unsigned short* Ab = A + (size_t)sA * blockIdx.z;
  const unsigned short* Bb = B + (size_t)sB * blockIdx.z;

  f32x4 acc[4][4];
#pragma unroll
  for (int i = 0; i < 4; ++i)
#pragma unroll
    for (int j = 0; j < 4; ++j)
      acc[i][j] = (f32x4){0.f, 0.f, 0.f, 0.f};

  const int nk = K >> 6;
  for (int kt = 0; kt < nk; ++kt) {
    __syncthreads();
    const int kb = kt << 6;
#pragma unroll
    for (int it = 0; it < 4; ++it) {
      int c = it * 256 + tid;
      int row = c >> 3;
      int lslot = (c & 7) ^ (row & 7);
      int ldsoff = (it * 256 + wave * 64) * 8;
      load_lds16(Ab + (size_t)(m0 + row) * lda + kb + lslot * 8, &As[ldsoff]);
      load_lds16(Bb + (size_t)(n0 + row) * ldb + kb + lslot * 8, &Bs[ldsoff]);
    }
    __syncthreads();
#pragma unroll
    for (int h = 0; h < 2; ++h) {
      bf16x8 af[4], bfr[4];
#pragma unroll
      for (int i = 0; i < 4; ++i) {
        int row = wm * 64 + i * 16 + (lane & 15);
        int pslot = (h * 4 + (lane >> 4)) ^ (row & 7);
        af[i] = *(const bf16x8*)&As[row * 64 + pslot * 8];
      }
#pragma unroll
      for (int j = 0; j < 4; ++j) {
        int row = wn * 64 + j * 16 + (lane & 15);
        int pslot = (h * 4 + (lane >> 4)) ^ (row & 7);
        bfr[j] = *(const bf16x8*)&Bs[row * 64 + pslot * 8];
      }
#pragma unroll
      for (int i = 0; i < 4; ++i)
#pragma unroll
        for (int j = 0; j < 4; ++j)
          acc[i][j] = __builtin_amdgcn_mfma_f32_16x16x32_bf16(af[i], bfr[j], acc[i][j], 0, 0, 0);
    }
  }

  // C/D layout: col = lane&15, row = (lane>>4)*4 + reg
  const int rsub = (lane >> 4) * 4;
  const int cbase = n0 + wn * 64 + (lane & 15);
  if (vtOut && n0 >= vtBase) {
    float bv[4] = {0.f, 0.f, 0.f, 0.f};
    if (bias) {
#pragma unroll
      for (int j = 0; j < 4; ++j) bv[j] = bias[cbase + j * 16];
    }
#pragma unroll
    for (int i = 0; i < 4; ++i) {
      int sg = m0 + wm * 64 + i * 16 + rsub;   // global row = batch*SEQ + s
      int bb = sg >> 11;
      int sl = sg & (SEQ - 1);
#pragma unroll
      for (int j = 0; j < 4; ++j) {
        int d = cbase + j * 16 - vtBase;
        u16x4 o;
#pragma unroll
        for (int r = 0; r < 4; ++r) o[r] = f2bf(acc[i][j][r] * scale + bv[j]);
        *(u16x4*)&vtOut[((size_t)bb * DM + d) * SEQ + sl] = o;
      }
    }
  } else if (outf32) {
    float* C = (float*)Cv + (size_t)sC * blockIdx.z;
#pragma unroll
    for (int i = 0; i < 4; ++i) {
      int rbase = m0 + wm * 64 + i * 16 + rsub;
#pragma unroll
      for (int j = 0; j < 4; ++j)
#pragma unroll
        for (int r = 0; r < 4; ++r)
          C[(size_t)(rbase + r) * ldc + cbase + j * 16] = acc[i][j][r] * scale;
    }
  } else {
    unsigned short* C = (unsigned short*)Cv + (size_t)sC * blockIdx.z;
    float bv[4] = {0.f, 0.f, 0.f, 0.f};
    if (bias) {
#pragma unroll
      for (int j = 0; j < 4; ++j) bv[j] = bias[cbase + j * 16];
    }
#pragma unroll
    for (int i = 0; i < 4; ++i) {
      int rbase = m0 + wm * 64 + i * 16 + rsub;
#pragma unroll
      for (int j = 0; j < 4; ++j)
#pragma unroll
        for (int r = 0; r < 4; ++r)
          C[(size_t)(rbase + r) * ldc + cbase + j * 16] = f2bf(acc[i][j][r] * scale + bv[j]);
    }
  }
}

// in-place row softmax over SEQ bf16 -> bf16 probs. one block per row.
__global__ __launch_bounds__(256) void softmax_kernel(unsigned short* __restrict__ Sc) {
  int row = blockIdx.x;
  int tid = threadIdx.x;
  unsigned short* sr = Sc + (size_t)row * SEQ;
  u16x8 raw = *(const u16x8*)&sr[tid * 8];
  float v[8];
#pragma unroll
  for (int j = 0; j < 8; ++j) v[j] = bf2f(raw[j]);
  float m = v[0];
#pragma unroll
  for (int j = 1; j < 8; ++j) m = fmaxf(m, v[j]);
#pragma unroll
  for (int off = 32; off; off >>= 1) m = fmaxf(m, __shfl_xor(m, off));
  __shared__ float red[8];
  int wv = tid >> 6;
  if ((tid & 63) == 0) red[wv] = m;
  __syncthreads();
  m = fmaxf(fmaxf(red[0], red[1]), fmaxf(red[2], red[3]));
  float s = 0.f;
#pragma unroll
  for (int j = 0; j < 8; ++j) { v[j] = __expf(v[j] - m); s += v[j]; }
#pragma unroll
  for (int off = 32; off; off >>= 1) s += __shfl_xor(s, off);
  if ((tid & 63) == 0) red[4 + wv] = s;
  __syncthreads();
  s = red[4] + red[5] + red[6] + red[7];
  float inv = 1.f / s;
  u16x8 o;
#pragma unroll
  for (int j = 0; j < 8; ++j) o[j] = f2bf(v[j] * inv);
  *(u16x8*)&sr[tid * 8] = o;
}

// y = LN(x + res(masked)) * g + b. x from f32 (xf) or bf16 (xb); out f32 or bf16.
__global__ __launch_bounds__(256) void ln_kernel(
    const float* __restrict__ xf, const unsigned short* __restrict__ xb,
    const unsigned short* __restrict__ res, int masked,
    const float* __restrict__ g, const float* __restrict__ be,
    float* __restrict__ outf, unsigned short* __restrict__ outb)
{
  int row = blockIdx.x;
  int s = row & (SEQ - 1);
  int tid = threadIdx.x;
  int d0 = tid * 4;
  float v[4];
  if (xf) {
    f32x4v t = ((const f32x4v*)(xf + (size_t)row * DM))[tid];
    v[0]=t[0]; v[1]=t[1]; v[2]=t[2]; v[3]=t[3];
  } else {
    u16x4 t = ((const u16x4*)(xb + (size_t)row * DM))[tid];
    v[0]=bf2f(t[0]); v[1]=bf2f(t[1]); v[2]=bf2f(t[2]); v[3]=bf2f(t[3]);
  }
  u16x4 rv = ((const u16x4*)(res + (size_t)row * DM))[tid];
#pragma unroll
  for (int j = 0; j < 4; ++j) {
    float r = bf2f(rv[j]);
    if (masked && (d0 + j) > s) r = 0.f;
    v[j] += r;
  }
  float s1 = v[0] + v[1] + v[2] + v[3];
  float s2 = v[0]*v[0] + v[1]*v[1] + v[2]*v[2] + v[3]*v[3];
#pragma unroll
  for (int off = 32; off; off >>= 1) { s1 += __shfl_xor(s1, off); s2 += __shfl_xor(s2, off); }
  __shared__ float red[8];
  int wv = tid >> 6;
  if ((tid & 63) == 0) { red[wv] = s1; red[4 + wv] = s2; }
  __syncthreads();
  s1 = red[0] + red[1] + red[2] + red[3];
  s2 = red[4] + red[5] + red[6] + red[7];
  float mean = s1 * (1.f / DM);
  float var = s2 * (1.f / DM) - mean * mean;
  float rstd = rsqrtf(var + 1e-5f);
  f32x4v gv = ((const f32x4v*)g)[tid];
  f32x4v bv = ((const f32x4v*)be)[tid];
  if (outf) {
    f32x4v o;
#pragma unroll
    for (int j = 0; j < 4; ++j) o[j] = (v[j] - mean) * rstd * gv[j] + bv[j];
    ((f32x4v*)(outf + (size_t)row * DM))[tid] = o;
  } else {
    u16x4 o;
#pragma unroll
    for (int j = 0; j < 4; ++j) o[j] = f2bf((v[j] - mean) * rstd * gv[j] + bv[j]);
    ((u16x4*)(outb + (size_t)row * DM))[tid] = o;
  }
}

extern "C" void kernel_launch(void* const* d_in, const int* in_sizes, int n_in,
                              void* d_out, int out_size, void* d_ws, size_t ws_size,
                              hipStream_t stream) {
  (void)in_sizes; (void)n_in; (void)out_size; (void)ws_size;
  const float* x     = (const float*)d_in[0];
  const float* wq_w  = (const float*)d_in[1];
  const float* wq_b  = (const float*)d_in[2];
  const float* wk_w  = (const float*)d_in[3];
  const float* wk_b  = (const float*)d_in[4];
  const float* wv_w  = (const float*)d_in[5];
  const float* wv_b  = (const float*)d_in[6];
  const float* lin_w = (const float*)d_in[7];
  const float* lin_b = (const float*)d_in[8];
  const float* g1    = (const float*)d_in[9];
  const float* b1    = (const float*)d_in[10];
  const float* g2    = (const float*)d_in[11];
  const float* b2    = (const float*)d_in[12];

  const size_t MB = 1ull << 20;
  char* ws = (char*)d_ws;
  // ---- workspace layout: NO overlays (peak 176 MiB) ----
  unsigned short* scP  = (unsigned short*)(ws);            // [0,32)   scores/probs bf16, in-place softmax
  unsigned short* attn = (unsigned short*)(ws + 32*MB);    // [32,48)
  unsigned short* x1   = (unsigned short*)(ws + 48*MB);    // [48,64)
  unsigned short* lin  = (unsigned short*)(ws + 64*MB);    // [64,80)
  unsigned short* xb   = (unsigned short*)(ws + 80*MB);    // [80,96)
  unsigned short* wqkvb= (unsigned short*)(ws + 96*MB);    // [96,102)
  unsigned short* lwb  = (unsigned short*)(ws + 102*MB);   // [102,104)
  float*          bqkv = (float*)(ws + 104*MB);            // [104,+12KiB)
  unsigned short* qkv  = (unsigned short*)(ws + 112*MB);   // [112,160)  (V cols unwritten/unused)
  unsigned short* vt   = (unsigned short*)(ws + 160*MB);   // [160,176)  V^T [NB][DM][SEQ]

  // 1. fused staging
  stage_kernel<<<2048, 256, 0, stream>>>(x, wq_w, wk_w, wv_w, lin_w, wq_b, wk_b, wv_b,
                                         xb, wqkvb, lwb, bqkv);

  // 2. fused QKV projection (64x24 = 1536 blocks, 2/CU); V blocks (n0>=2048) write V^T directly
  gemm_bt<<<dim3(64, 24, 1), 256, 0, stream>>>(xb, DM, 0, wqkvb, DM, 0, qkv, 3 * DM, 0,
                                               DM, bqkv, 1.f, 0, 0, vt, 2 * DM);

  const float scale = 0.03125f;  // 1/sqrt(1024)
  // 3. scores = (Q K^T) * scale -> bf16 (16x16x4 = 1024 blocks)
  gemm_bt<<<dim3(16, 16, NB), 256, 0, stream>>>(
      qkv, 3 * DM, (long)SEQ * 3 * DM,
      qkv + DM, 3 * DM, (long)SEQ * 3 * DM,
      scP, SEQ, (long)SEQ * SEQ, DM, nullptr, scale, 0, 0, nullptr, 0);
  // 4. softmax in-place
  softmax_kernel<<<NB * SEQ, 256, 0, stream>>>(scP);
  // 5. attn = P * (V^T)^T with tril tile-skip
  gemm_bt<<<dim3(16, 8, NB), 256, 0, stream>>>(
      scP, SEQ, (long)SEQ * SEQ,
      vt, SEQ, (long)DM * SEQ,
      attn, DM, (long)SEQ * DM, SEQ, nullptr, 1.f, 0, 1, nullptr, 0);

  // 6. LN1(xb + tril(attn)) -> x1 (bf16)
  ln_kernel<<<NB * SEQ, 256, 0, stream>>>(nullptr, xb, attn, 1, g1, b1, nullptr, x1);
  // 7. linear = x1 * lin_w^T + lin_b  (512 blocks, 2/CU)
  gemm_bt<<<dim3(64, 8, 1), 256, 0, stream>>>(x1, DM, 0, lwb, DM, 0, lin, DM, 0, DM,
                                              lin_b, 1.f, 0, 0, nullptr, 0);
  // 8. LN2(x1 + linear) -> d_out (f32)
  ln_kernel<<<NB * SEQ, 256, 0, stream>>>(nullptr, x1, lin, 0, g2, b2, (float*)d_out, nullptr);
}